// Round 12
// baseline (311.953 us; speedup 1.0000x reference)
//
#include <hip/hip_runtime.h>
#include <math.h>

// Problem constants
#define BB 2
#define LL 1024
#define HH 1024
#define NH 16
#define DD 64
#define HD (NH * DD)   // 1024
#define MM (BB * LL)   // 2048
#define RCT 32         // recurrence chunk length staged in LDS
#define KEXT 3072      // extended K for f16 hi/lo split GEMM (3 x 1024)
#define NBK 1152       // k-GEMM B rows: 1024 k + 16 alpha + 16 beta + 96 pad

typedef _Float16 f16x8 __attribute__((ext_vector_type(8)));
typedef _Float16 f16x4 __attribute__((ext_vector_type(4)));
typedef float f32x4 __attribute__((ext_vector_type(4)));

// ---------------------------------------------------------------------------
// async global->LDS, 16B per lane; LDS dest = wave-uniform base + lane*16
// ---------------------------------------------------------------------------
__device__ __forceinline__ void load_lds16(const void* g, void* l) {
    __builtin_amdgcn_global_load_lds(
        (const __attribute__((address_space(1))) void*)g,
        (__attribute__((address_space(3))) void*)l, 16, 0, 0);
}

// ---------------------------------------------------------------------------
// Conversions (unchanged). Only k/alpha/beta compound through the recurrence
// -> 3-split f16 (K=3072); q (readout) and v (additive) are plain f16.
// ---------------------------------------------------------------------------
__global__ __launch_bounds__(256) void convert_front(
    const float* __restrict__ hs,
    const float* __restrict__ Wq, const float* __restrict__ Wk,
    const float* __restrict__ Wv, const float* __restrict__ Wa,
    const float* __restrict__ Wb, const float* __restrict__ Wo,
    _Float16* __restrict__ Ae3, _Float16* __restrict__ Ah,
    _Float16* __restrict__ Bk, _Float16* __restrict__ Bqv,
    _Float16* __restrict__ Be2)
{
    const int blk = blockIdx.x;
    const int t = threadIdx.x;

    if (blk < 2048) {             // hs -> Ae3 (3-split) + Ah (hi)
        float4 x = *(const float4*)(hs + (size_t)blk * 1024 + t * 4);
        x.x *= 16.f; x.y *= 16.f; x.z *= 16.f; x.w *= 16.f;
        f16x4 h, l;
        h[0] = (_Float16)x.x; l[0] = (_Float16)(x.x - (float)h[0]);
        h[1] = (_Float16)x.y; l[1] = (_Float16)(x.y - (float)h[1]);
        h[2] = (_Float16)x.z; l[2] = (_Float16)(x.z - (float)h[2]);
        h[3] = (_Float16)x.w; l[3] = (_Float16)(x.w - (float)h[3]);
        _Float16* base = Ae3 + (size_t)blk * KEXT + t * 4;
        *(f16x4*)(base)        = h;
        *(f16x4*)(base + 1024) = l;
        *(f16x4*)(base + 2048) = h;
        *(f16x4*)(Ah + (size_t)blk * 1024 + t * 4) = h;
        return;
    }
    if (blk < 3200) {             // Wk/Wa/Wb -> Bk (3-split, B-order)
        const int n = blk - 2048;
        const float* src = nullptr;
        if (n < 1024)      src = Wk + (size_t)n * 1024;
        else if (n < 1040) src = Wa + (size_t)(n - 1024) * 1024;
        else if (n < 1056) src = Wb + (size_t)(n - 1040) * 1024;
        float4 x = src ? *(const float4*)(src + t * 4)
                       : make_float4(0.f, 0.f, 0.f, 0.f);
        x.x *= 64.f; x.y *= 64.f; x.z *= 64.f; x.w *= 64.f;
        f16x4 h, l;
        h[0] = (_Float16)x.x; l[0] = (_Float16)(x.x - (float)h[0]);
        h[1] = (_Float16)x.y; l[1] = (_Float16)(x.y - (float)h[1]);
        h[2] = (_Float16)x.z; l[2] = (_Float16)(x.z - (float)h[2]);
        h[3] = (_Float16)x.w; l[3] = (_Float16)(x.w - (float)h[3]);
        _Float16* base = Bk + (size_t)n * KEXT + t * 4;
        *(f16x4*)(base)        = h;
        *(f16x4*)(base + 1024) = h;
        *(f16x4*)(base + 2048) = l;
        return;
    }
    if (blk < 5248) {             // Wq|Wv -> Bqv (hi only)
        const int n = blk - 3200;
        const float* src = (n < 1024) ? Wq + (size_t)n * 1024
                                      : Wv + (size_t)(n - 1024) * 1024;
        float4 x = *(const float4*)(src + t * 4);
        f16x4 h;
        h[0] = (_Float16)(x.x * 64.f);
        h[1] = (_Float16)(x.y * 64.f);
        h[2] = (_Float16)(x.z * 64.f);
        h[3] = (_Float16)(x.w * 64.f);
        *(f16x4*)(Bqv + (size_t)n * 1024 + t * 4) = h;
        return;
    }
    {                             // Wo -> Be2 (hi only)
        const int n = blk - 5248;
        float4 x = *(const float4*)(Wo + (size_t)n * 1024 + t * 4);
        f16x4 h;
        h[0] = (_Float16)(x.x * 64.f);
        h[1] = (_Float16)(x.y * 64.f);
        h[2] = (_Float16)(x.z * 64.f);
        h[3] = (_Float16)(x.w * 64.f);
        *(f16x4*)(Be2 + (size_t)n * 1024 + t * 4) = h;
    }
}

// ---------------------------------------------------------------------------
// MERGED projection GEMM (unchanged from r11): 544 blocks.
//   blk <  288: k+ab part — Ae3 @ Bk^T, K=3072, 128x64 tile.
//   blk >= 288: q|v part  — Ah @ Bqv^T, K=1024, 128x128 tile.
// ---------------------------------------------------------------------------
__global__ __launch_bounds__(256) void mfma_gemm_proj(
    const _Float16* __restrict__ Ae3, const _Float16* __restrict__ Bk,
    const _Float16* __restrict__ Ah, const _Float16* __restrict__ Bqv,
    float* __restrict__ qkv, float* __restrict__ ab,
    const float* __restrict__ bq, const float* __restrict__ bk,
    const float* __restrict__ bv)
{
    __shared__ __align__(16) _Float16 As[2][128 * 32];
    __shared__ __align__(16) _Float16 Bs[2][128 * 32];

    const int blk = blockIdx.x;
    const int tid = threadIdx.x;
    const int wave = tid >> 6;
    const int lane = tid & 63;
    const int srow = lane >> 2;
    const int scol = (lane & 3) * 8;
    const int fm = lane & 15;
    const int fq = (lane >> 4) * 8;
    const int rquad = (lane >> 4) * 4;

    if (blk < 288) {
        const int bm = (blk / 18) * 128;
        const int bn = (blk % 18) * 64;
        const int wr = (wave >> 1) * 64;
        const int wc = (wave & 1) * 32;

        const _Float16* gA0 = Ae3 + (size_t)(bm + wave * 32 + srow) * KEXT + scol;
        const _Float16* gA1 = gA0 + (size_t)16 * KEXT;
        const _Float16* gB0 = Bk + (size_t)(bn + wave * 16 + srow) * KEXT + scol;
        _Float16* lA0_0 = &As[0][(wave * 32) * 32];
        _Float16* lA1_0 = &As[0][(wave * 32 + 16) * 32];
        _Float16* lB0_0 = &Bs[0][(wave * 16) * 32];
        _Float16* lA0_1 = &As[1][(wave * 32) * 32];
        _Float16* lA1_1 = &As[1][(wave * 32 + 16) * 32];
        _Float16* lB0_1 = &Bs[1][(wave * 16) * 32];

        f32x4 acc[4][2] = {};

        for (int k0 = 0; k0 < KEXT; k0 += 64) {
            load_lds16(gA0 + k0,      lA0_0);
            load_lds16(gA1 + k0,      lA1_0);
            load_lds16(gB0 + k0,      lB0_0);
            load_lds16(gA0 + k0 + 32, lA0_1);
            load_lds16(gA1 + k0 + 32, lA1_1);
            load_lds16(gB0 + k0 + 32, lB0_1);
            __syncthreads();

            #pragma unroll
            for (int s = 0; s < 2; ++s) {
                f16x8 a[4], b[2];
                #pragma unroll
                for (int mt = 0; mt < 4; ++mt)
                    a[mt] = *(const f16x8*)&As[s][(wr + mt * 16 + fm) * 32 + fq];
                #pragma unroll
                for (int nt = 0; nt < 2; ++nt)
                    b[nt] = *(const f16x8*)&Bs[s][(wc + nt * 16 + fm) * 32 + fq];
                #pragma unroll
                for (int mt = 0; mt < 4; ++mt)
                    #pragma unroll
                    for (int nt = 0; nt < 2; ++nt)
                        acc[mt][nt] = __builtin_amdgcn_mfma_f32_16x16x32_f16(
                            a[mt], b[nt], acc[mt][nt], 0, 0, 0);
            }
            __syncthreads();
        }

        #pragma unroll
        for (int mt = 0; mt < 4; ++mt) {
            #pragma unroll
            for (int nt = 0; nt < 2; ++nt) {
                const int col = bn + wc + nt * 16 + fm;
                #pragma unroll
                for (int i = 0; i < 4; ++i) {
                    const int row = bm + wr + mt * 16 + rquad + i;
                    float val = acc[mt][nt][i] * (1.0f / 1024.0f);
                    if (col < 1024)
                        qkv[(size_t)row * 3072 + 1024 + col] = val + bk[col];
                    else if (col < 1040)
                        ab[(size_t)row * 32 + (col - 1024)] =
                            1.f / (1.f + expf(-val));
                    else if (col < 1056)
                        ab[(size_t)row * 32 + 16 + (col - 1040)] =
                            fmaxf(val, 0.f) + log1pf(expf(-fabsf(val)));
                }
            }
        }
    } else {
        const int n = blk - 288;
        const int bm = (n / 16) * 128;
        const int bn = (n % 16) * 128;
        const int wr = (wave >> 1) * 64;
        const int wc = (wave & 1) * 64;

        const _Float16* gA0 = Ah + (size_t)(bm + wave * 32 + srow) * 1024 + scol;
        const _Float16* gA1 = gA0 + (size_t)16 * 1024;
        const _Float16* gB0 = Bqv + (size_t)(bn + wave * 32 + srow) * 1024 + scol;
        const _Float16* gB1 = gB0 + (size_t)16 * 1024;
        _Float16* lA0_0 = &As[0][(wave * 32) * 32];
        _Float16* lA1_0 = &As[0][(wave * 32 + 16) * 32];
        _Float16* lB0_0 = &Bs[0][(wave * 32) * 32];
        _Float16* lB1_0 = &Bs[0][(wave * 32 + 16) * 32];
        _Float16* lA0_1 = &As[1][(wave * 32) * 32];
        _Float16* lA1_1 = &As[1][(wave * 32 + 16) * 32];
        _Float16* lB0_1 = &Bs[1][(wave * 32) * 32];
        _Float16* lB1_1 = &Bs[1][(wave * 32 + 16) * 32];

        f32x4 acc[4][4] = {};

        for (int k0 = 0; k0 < 1024; k0 += 64) {
            load_lds16(gA0 + k0,      lA0_0);
            load_lds16(gA1 + k0,      lA1_0);
            load_lds16(gB0 + k0,      lB0_0);
            load_lds16(gB1 + k0,      lB1_0);
            load_lds16(gA0 + k0 + 32, lA0_1);
            load_lds16(gA1 + k0 + 32, lA1_1);
            load_lds16(gB0 + k0 + 32, lB0_1);
            load_lds16(gB1 + k0 + 32, lB1_1);
            __syncthreads();

            #pragma unroll
            for (int s = 0; s < 2; ++s) {
                f16x8 a[4], b[4];
                #pragma unroll
                for (int mt = 0; mt < 4; ++mt)
                    a[mt] = *(const f16x8*)&As[s][(wr + mt * 16 + fm) * 32 + fq];
                #pragma unroll
                for (int nt = 0; nt < 4; ++nt)
                    b[nt] = *(const f16x8*)&Bs[s][(wc + nt * 16 + fm) * 32 + fq];
                #pragma unroll
                for (int mt = 0; mt < 4; ++mt)
                    #pragma unroll
                    for (int nt = 0; nt < 4; ++nt)
                        acc[mt][nt] = __builtin_amdgcn_mfma_f32_16x16x32_f16(
                            a[mt], b[nt], acc[mt][nt], 0, 0, 0);
            }
            __syncthreads();
        }

        #pragma unroll
        for (int mt = 0; mt < 4; ++mt) {
            #pragma unroll
            for (int nt = 0; nt < 4; ++nt) {
                const int col = bn + wc + nt * 16 + fm;
                #pragma unroll
                for (int i = 0; i < 4; ++i) {
                    const int row = bm + wr + mt * 16 + rquad + i;
                    float val = acc[mt][nt][i] * (1.0f / 1024.0f);
                    if (col < 1024)
                        qkv[(size_t)row * 3072 + col] = val + bq[col];
                    else
                        qkv[(size_t)row * 3072 + 1024 + col] = val + bv[col - 1024];
                }
            }
        }
    }
}

// ---------------------------------------------------------------------------
// Out-projection MFMA GEMM (unchanged): plain f16, K=1024, 128x64, BK=64.
// ---------------------------------------------------------------------------
__global__ __launch_bounds__(256) void mfma_gemm_out(
    const _Float16* __restrict__ Ae2, const _Float16* __restrict__ Be2,
    float* __restrict__ outp, const float* __restrict__ bo)
{
    __shared__ __align__(16) _Float16 As[2][128 * 32];
    __shared__ __align__(16) _Float16 Bs[2][64 * 32];

    const int tid = threadIdx.x;
    const int wave = tid >> 6;
    const int lane = tid & 63;
    const int bm = blockIdx.y * 128;
    const int bn = blockIdx.x * 64;
    const int wr = (wave >> 1) * 64;
    const int wc = (wave & 1) * 32;

    const int srow = lane >> 2;
    const int scol = (lane & 3) * 8;
    const _Float16* gA0 = Ae2 + (size_t)(bm + wave * 32 + srow) * 1024 + scol;
    const _Float16* gA1 = gA0 + (size_t)16 * 1024;
    const _Float16* gB0 = Be2 + (size_t)(bn + wave * 16 + srow) * 1024 + scol;
    _Float16* lA0_0 = &As[0][(wave * 32) * 32];
    _Float16* lA1_0 = &As[0][(wave * 32 + 16) * 32];
    _Float16* lB0_0 = &Bs[0][(wave * 16) * 32];
    _Float16* lA0_1 = &As[1][(wave * 32) * 32];
    _Float16* lA1_1 = &As[1][(wave * 32 + 16) * 32];
    _Float16* lB0_1 = &Bs[1][(wave * 16) * 32];

    const int fm = lane & 15;
    const int fq = (lane >> 4) * 8;

    f32x4 acc[4][2] = {};

    for (int k0 = 0; k0 < 1024; k0 += 64) {
        load_lds16(gA0 + k0,      lA0_0);
        load_lds16(gA1 + k0,      lA1_0);
        load_lds16(gB0 + k0,      lB0_0);
        load_lds16(gA0 + k0 + 32, lA0_1);
        load_lds16(gA1 + k0 + 32, lA1_1);
        load_lds16(gB0 + k0 + 32, lB0_1);
        __syncthreads();

        #pragma unroll
        for (int s = 0; s < 2; ++s) {
            f16x8 a[4], b[2];
            #pragma unroll
            for (int mt = 0; mt < 4; ++mt)
                a[mt] = *(const f16x8*)&As[s][(wr + mt * 16 + fm) * 32 + fq];
            #pragma unroll
            for (int nt = 0; nt < 2; ++nt)
                b[nt] = *(const f16x8*)&Bs[s][(wc + nt * 16 + fm) * 32 + fq];
            #pragma unroll
            for (int mt = 0; mt < 4; ++mt)
                #pragma unroll
                for (int nt = 0; nt < 2; ++nt)
                    acc[mt][nt] = __builtin_amdgcn_mfma_f32_16x16x32_f16(
                        a[mt], b[nt], acc[mt][nt], 0, 0, 0);
        }
        __syncthreads();
    }

    const int rquad = (lane >> 4) * 4;
    #pragma unroll
    for (int mt = 0; mt < 4; ++mt) {
        #pragma unroll
        for (int nt = 0; nt < 2; ++nt) {
            const int col = bn + wc + nt * 16 + fm;
            #pragma unroll
            for (int i = 0; i < 4; ++i) {
                const int row = bm + wr + mt * 16 + rquad + i;
                outp[(size_t)row * 1024 + col] = acc[mt][nt][i] * 64.f + bo[col];
            }
        }
    }
}

// ---------------------------------------------------------------------------
// DPP 16-lane reduction (xor1, xor2, row_ror:4, row_ror:8 -> all lanes hold sum)
// ---------------------------------------------------------------------------
template <int CTRL>
__device__ __forceinline__ float dpp_addf(float x) {
    int y = __builtin_amdgcn_update_dpp(0, __builtin_bit_cast(int, x),
                                        CTRL, 0xF, 0xF, true);
    return x + __builtin_bit_cast(float, y);
}
__device__ __forceinline__ float red16(float x) {
    x = dpp_addf<0xB1>(x);
    x = dpp_addf<0x4E>(x);
    x = dpp_addf<0x124>(x);
    x = dpp_addf<0x128>(x);
    return x;
}

// ---------------------------------------------------------------------------
// Gated delta recurrence with OFF-CHAIN red16 (lookahead, in-kernel Gram).
// At step t (S = S_{t-1}, carried skc = sk_t):
//   cf_t = b_t(v_t - a_t*skc)                          [serial: 2 ops]
//   dn = red16(S_{t-1} . k_{t+1})   — pre-update S, so its DPP chain
//   gk = red16(k_t . k_{t+1})         overlaps the S-update + o-dot below
//   S_t = a_t*S + cf_t*k_t ; o_t = red16(S_t . q_t)
//   skc' = a_t*dn + cf_t*gk          [serial: 2 FMAs, dn/gk long since ready]
// Chunk seam: k_{t+1} for t=31 lives in the next chunk -> one serial red16
// per chunk after the barrier. r11 structure otherwise verbatim.
// ---------------------------------------------------------------------------
__global__ __launch_bounds__(64) void gdn_recurrence(
    const float* __restrict__ qkv, const float* __restrict__ ab,
    float* __restrict__ att)
{
    __shared__ __align__(16) float ks[2][RCT][64];
    __shared__ __align__(16) float qs[2][RCT][64];
    __shared__ __align__(16) float vs_[2][RCT][4];
    __shared__ __align__(16) float gab[2][RCT][2];

    const int blk = blockIdx.x;
    const int bh = blk & 31;          // chain (XCD co-location)
    const int s  = blk >> 5;          // row-slice 0..15
    const int b  = bh >> 4;
    const int h  = bh & 15;
    const int lane = threadIdx.x;
    const int rl = lane >> 4;         // local row 0..3
    const int el = lane & 15;         // e-slice
    const int e0 = el * 4;
    const int r0 = s * 4;

    const float* qb  = qkv + (size_t)b * LL * 3072 + h * 64;
    const float* kb  = qb + 1024;
    const float* vb  = qb + 2048 + r0;
    const float* abp = ab + (size_t)b * LL * 32 + h;
    float* op = att + ((size_t)(b * NH + h) * DD + r0 + rl) * LL;

    const int st = lane >> 4;          // t-within-4 for staging
    const int sd = (lane & 15) * 4;    // d offset

    float S0 = 0.f, S1 = 0.f, S2 = 0.f, S3 = 0.f;
    float skc = 0.f;                   // sk for the next consumed step (S=0 -> 0)

    // ---- async-stage k/q chunk 0, reg-load v/ab chunk 0 ----
    {
        const size_t ro = (size_t)st * 3072 + sd;
        #pragma unroll
        for (int m = 0; m < 8; ++m) {
            load_lds16(kb + ro + (size_t)m * 4 * 3072, &ks[0][m * 4][0]);
            load_lds16(qb + ro + (size_t)m * 4 * 3072, &qs[0][m * 4][0]);
        }
        float4 pv = make_float4(0.f,0.f,0.f,0.f);
        if (lane < RCT) pv = *(const float4*)(vb + (size_t)lane * 3072);
        float pab = (lane < 32) ? abp[(size_t)lane * 32]
                                : abp[(size_t)(lane - 32) * 32 + 16];
        if (lane < RCT) *(float4*)&vs_[0][lane][0] = pv;
        if (lane < 32) gab[0][lane][0] = pab;
        else           gab[0][lane - 32][1] = pab;
    }
    __syncthreads();

    const int NCHUNK = LL / RCT;
    for (int c = 0; c < NCHUNK; ++c) {
        const int cur = c & 1, nxt = cur ^ 1;
        const bool more = (c + 1 < NCHUNK);

        // issue async staging for chunk c+1; tiny reg prefetch for v/ab
        float4 pv = make_float4(0.f,0.f,0.f,0.f);
        float pab = 0.f;
        if (more) {
            const size_t t0 = (size_t)(c + 1) * RCT;
            const size_t ro = (t0 + st) * 3072 + sd;
            #pragma unroll
            for (int m = 0; m < 8; ++m) {
                load_lds16(kb + ro + (size_t)m * 4 * 3072, &ks[nxt][m * 4][0]);
                load_lds16(qb + ro + (size_t)m * 4 * 3072, &qs[nxt][m * 4][0]);
            }
            if (lane < RCT) pv = *(const float4*)(vb + (t0 + lane) * 3072);
            pab = (lane < 32) ? abp[(t0 + lane) * 32]
                              : abp[(t0 + lane - 32) * 32 + 16];
        }

        // ---- 32 steps, distance-2 LDS->reg prefetch (4-slot circular) ----
        float4 kr[4], qr[4];
        float vr[4];
        float2 abr[4];
        #pragma unroll
        for (int i = 0; i < 2; ++i) {
            kr[i] = *(const float4*)&ks[cur][i][e0];
            qr[i] = *(const float4*)&qs[cur][i][e0];
            vr[i] = vs_[cur][i][rl];
            abr[i] = *(const float2*)&gab[cur][i][0];
        }

        float o0 = 0.f, o1 = 0.f, o2 = 0.f;
        #pragma unroll 4
        for (int t = 0; t < RCT; ++t) {
            const int tf = (t + 2 < RCT) ? t + 2 : RCT - 1;
            kr[(t + 2) & 3] = *(const float4*)&ks[cur][tf][e0];
            qr[(t + 2) & 3] = *(const float4*)&qs[cur][tf][e0];
            vr[(t + 2) & 3] = vs_[cur][tf][rl];
            abr[(t + 2) & 3] = *(const float2*)&gab[cur][tf][0];

            const float4 kc = kr[t & 3];
            const float4 kn = kr[(t + 1) & 3];   // k_{t+1} (valid t<31)
            const float4 qc = qr[t & 3];
            const float vc = vr[t & 3];
            const float ac = abr[t & 3].x;
            const float bc = abr[t & 3].y;

            // serial: cf from carried skc
            const float cf = bc * fmaf(-ac, skc, vc);

            // off-chain dots (dn uses PRE-update S)
            float d0 = fmaf(S1, kn.y, S0 * kn.x);
            float d1 = fmaf(S3, kn.w, S2 * kn.z);
            float dn = red16(d0 + d1);
            float g0 = fmaf(kc.y, kn.y, kc.x * kn.x);
            float g1 = fmaf(kc.w, kn.w, kc.z * kn.z);
            float gk = red16(g0 + g1);

            // state update
            S0 = fmaf(ac, S0, cf * kc.x);
            S1 = fmaf(ac, S1, cf * kc.y);
            S2 = fmaf(ac, S2, cf * kc.z);
            S3 = fmaf(ac, S3, cf * kc.w);

            // output
            float q0 = fmaf(S1, qc.y, S0 * qc.x);
            float q1 = fmaf(S3, qc.w, S2 * qc.z);
            float o = red16(q0 + q1);

            const int ph = t & 3;
            if (ph == 0) o0 = o;
            else if (ph == 1) o1 = o;
            else if (ph == 2) o2 = o;
            else if (el == 0)
                *(float4*)(op + c * RCT + t - 3) = make_float4(o0, o1, o2, o);

            // serial tail: sk_{t+1} = a_t*dn + cf_t*gk (garbage at t=31,
            // overwritten by the seam below)
            skc = fmaf(ac, dn, cf * gk);
        }

        // commit v/ab prefetch into next buffer, then publish
        if (more) {
            if (lane < RCT) *(float4*)&vs_[nxt][lane][0] = pv;
            if (lane < 32) gab[nxt][lane][0] = pab;
            else           gab[nxt][lane - 32][1] = pab;
        }
        __syncthreads();

        // seam: true sk for the next chunk's first step (staged data now visible)
        if (more) {
            const float4 k0n = *(const float4*)&ks[nxt][0][e0];
            float s0p = fmaf(S1, k0n.y, S0 * k0n.x);
            float s1p = fmaf(S3, k0n.w, S2 * k0n.z);
            skc = red16(s0p + s1p);
        }
    }
}

// ---------------------------------------------------------------------------
// Fused: residual depthwise causal conv (bug-compat reshaped view) +
// transpose back + f16 convert (hi only) for the out-projection A matrix.
// ---------------------------------------------------------------------------
__global__ __launch_bounds__(256) void conv_convert(
    const float* __restrict__ att, const float* __restrict__ Wconv,
    _Float16* __restrict__ Ae2)
{
    __shared__ float yt[112][68];
    const int lb = blockIdx.x;
    const int h  = blockIdx.y;
    const int b  = blockIdx.z;
    const int tid = threadIdx.x;

    {
        const int d = tid >> 2;
        const int part = tid & 3;
        const float* src  = att + ((size_t)(b * NH + h) * DD + d) * LL;
        const float* srcm = src - (size_t)DD * LL;
        #pragma unroll
        for (int m = 0; m < 7; ++m) {
            const int off = (part * 7 + m) * 4;
            const int lg = lb * 64 - 48 + off;
            float4 v;
            if (lg >= 0)      v = *(const float4*)(src + lg);
            else if (h > 0)   v = *(const float4*)(srcm + lg + 1024);
            else              v = make_float4(0.f, 0.f, 0.f, 0.f);
            yt[off + 0][d] = v.x; yt[off + 1][d] = v.y;
            yt[off + 2][d] = v.z; yt[off + 3][d] = v.w;
        }
    }
    __syncthreads();

    float4 w[4];
    #pragma unroll
    for (int k = 0; k < 4; ++k)
        w[k] = ((const float4*)Wconv)[tid * 4 + k];

    const int d0 = (tid & 15) * 4;
    const int lq = tid >> 4;
    const float sc = 1.f / 4096.f;

    #pragma unroll
    for (int rr = 0; rr < 4; ++rr) {
        const int ll = rr * 16 + lq;
        float y0[4], y1[4], y2[4], y3[4];
        *(float4*)y0 = *(const float4*)&yt[ll +  0][d0];
        *(float4*)y1 = *(const float4*)&yt[ll + 16][d0];
        *(float4*)y2 = *(const float4*)&yt[ll + 32][d0];
        *(float4*)y3 = *(const float4*)&yt[ll + 48][d0];
        f16x4 hi;
        #pragma unroll
        for (int k = 0; k < 4; ++k) {
            float acc = y3[k];
            acc = fmaf(w[k].x, y0[k], acc);
            acc = fmaf(w[k].y, y1[k], acc);
            acc = fmaf(w[k].z, y2[k], acc);
            acc = fmaf(w[k].w, y3[k], acc);
            hi[k] = (_Float16)(acc * sc);
        }
        const size_t row = (size_t)b * 1024 + h * 64 + lb * 4 + rr;
        *(f16x4*)(Ae2 + row * 1024 + tid * 4) = hi;
    }
}

// ---------------------------------------------------------------------------
extern "C" void kernel_launch(void* const* d_in, const int* in_sizes, int n_in,
                              void* d_out, int out_size, void* d_ws, size_t ws_size,
                              hipStream_t stream)
{
    const float* hs    = (const float*)d_in[0];
    const float* Wq    = (const float*)d_in[1];
    const float* bq    = (const float*)d_in[2];
    const float* Wk    = (const float*)d_in[3];
    const float* bk    = (const float*)d_in[4];
    const float* Wv    = (const float*)d_in[5];
    const float* bv    = (const float*)d_in[6];
    const float* Wa    = (const float*)d_in[7];
    const float* Wb    = (const float*)d_in[8];
    const float* Wconv = (const float*)d_in[9];
    const float* Wo    = (const float*)d_in[10];
    const float* bo    = (const float*)d_in[11];
    float* out = (float*)d_out;

    // workspace layout (~68 MB)
    char* w = (char*)d_ws;
    float* qkv = (float*)w;        w += (size_t)MM * 3072 * 4;      // 25.2 MB
    float* att = (float*)w;        w += (size_t)MM * 1024 * 4;      //  8.4 MB ([B][NH][D][L])
    float* ab  = (float*)w;        w += (size_t)MM * 32 * 4;        //  0.26 MB
    _Float16* Ae3 = (_Float16*)w;  w += (size_t)MM * KEXT * 2;      // 12.6 MB
    _Float16* Ah  = (_Float16*)w;  w += (size_t)MM * 1024 * 2;      //  4.2 MB
    _Float16* Bk  = (_Float16*)w;  w += (size_t)NBK * KEXT * 2;     //  7.1 MB
    _Float16* Bqv = (_Float16*)w;  w += (size_t)2048 * 1024 * 2;    //  4.2 MB
    _Float16* Ae2 = (_Float16*)w;  w += (size_t)MM * 1024 * 2;      //  4.2 MB
    _Float16* Be2 = (_Float16*)w;  w += (size_t)1024 * 1024 * 2;    //  2.1 MB

    // 1) conversions (hs->Ae3+Ah, Wk/Wa/Wb->Bk, Wq|Wv->Bqv, Wo->Be2)
    hipLaunchKernelGGL(convert_front, dim3(6272), dim3(256), 0, stream,
                       hs, Wq, Wk, Wv, Wa, Wb, Wo, Ae3, Ah, Bk, Bqv, Be2);

    // 2) merged projection GEMM (k+ab 288 blocks | q+v 256 blocks)
    hipLaunchKernelGGL(mfma_gemm_proj, dim3(544), dim3(256), 0, stream,
                       Ae3, Bk, Ah, Bqv, qkv, ab, bq, bk, bv);

    // 3) gated delta recurrence (off-chain red16 lookahead, 512 blocks)
    hipLaunchKernelGGL(gdn_recurrence, dim3(512), dim3(64), 0, stream, qkv, ab, att);

    // 4) fused conv + transpose + f16 convert (hi only, writes Ae2)
    hipLaunchKernelGGL(conv_convert, dim3(16, 16, BB), dim3(256), 0, stream,
                       att, Wconv, Ae2);

    // 5) out-projection (plain f16, K=1024, 128x64 tiles -> 256 blocks)
    hipLaunchKernelGGL(mfma_gemm_out, dim3(1024 / 64, MM / 128), dim3(256), 0, stream,
                       Ae2, Be2, out, bo);
}

// Round 13
// 292.802 us; speedup vs baseline: 1.0654x; 1.0654x over previous
//
#include <hip/hip_runtime.h>
#include <math.h>

// Problem constants
#define BB 2
#define LL 1024
#define HH 1024
#define NH 16
#define DD 64
#define HD (NH * DD)   // 1024
#define MM (BB * LL)   // 2048
#define RCT 32         // recurrence chunk length staged in LDS
#define KEXT 3072      // extended K for f16 hi/lo split GEMM (3 x 1024)
#define NBK 1088       // k-GEMM B rows: 1024 k + 16 alpha + 16 beta + 32 pad

typedef _Float16 f16x8 __attribute__((ext_vector_type(8)));
typedef _Float16 f16x4 __attribute__((ext_vector_type(4)));
typedef float f32x4 __attribute__((ext_vector_type(4)));

// ---------------------------------------------------------------------------
// async global->LDS, 16B per lane; LDS dest = wave-uniform base + lane*16
// ---------------------------------------------------------------------------
__device__ __forceinline__ void load_lds16(const void* g, void* l) {
    __builtin_amdgcn_global_load_lds(
        (const __attribute__((address_space(1))) void*)g,
        (__attribute__((address_space(3))) void*)l, 16, 0, 0);
}

// ---------------------------------------------------------------------------
// Conversions. Only k/alpha/beta compound through the recurrence -> 3-split
// f16 (K=3072); q (readout) and v (additive) are plain f16 and read the hi
// section of Ae3 directly (row stride KEXT) — no separate Ah copy.
//   blocks [0,2048):        hs -> Ae3 (x16, [hi|lo|hi])
//   blocks [2048,3136):     Wk/Wa/Wb -> Bk (x64, [hi|hi|lo]), rows>=1056 zero
//   blocks [3136,5184):     Wq|Wv -> Bqv (x64, hi only)
//   blocks [5184,6208):     Wo -> Be2 (x64, hi only)
// ---------------------------------------------------------------------------
__global__ __launch_bounds__(256) void convert_front(
    const float* __restrict__ hs,
    const float* __restrict__ Wq, const float* __restrict__ Wk,
    const float* __restrict__ Wv, const float* __restrict__ Wa,
    const float* __restrict__ Wb, const float* __restrict__ Wo,
    _Float16* __restrict__ Ae3,
    _Float16* __restrict__ Bk, _Float16* __restrict__ Bqv,
    _Float16* __restrict__ Be2)
{
    const int blk = blockIdx.x;
    const int t = threadIdx.x;

    if (blk < 2048) {             // hs -> Ae3 (3-split)
        float4 x = *(const float4*)(hs + (size_t)blk * 1024 + t * 4);
        x.x *= 16.f; x.y *= 16.f; x.z *= 16.f; x.w *= 16.f;
        f16x4 h, l;
        h[0] = (_Float16)x.x; l[0] = (_Float16)(x.x - (float)h[0]);
        h[1] = (_Float16)x.y; l[1] = (_Float16)(x.y - (float)h[1]);
        h[2] = (_Float16)x.z; l[2] = (_Float16)(x.z - (float)h[2]);
        h[3] = (_Float16)x.w; l[3] = (_Float16)(x.w - (float)h[3]);
        _Float16* base = Ae3 + (size_t)blk * KEXT + t * 4;
        *(f16x4*)(base)        = h;
        *(f16x4*)(base + 1024) = l;
        *(f16x4*)(base + 2048) = h;
        return;
    }
    if (blk < 3136) {             // Wk/Wa/Wb -> Bk (3-split, B-order)
        const int n = blk - 2048;
        const float* src = nullptr;
        if (n < 1024)      src = Wk + (size_t)n * 1024;
        else if (n < 1040) src = Wa + (size_t)(n - 1024) * 1024;
        else if (n < 1056) src = Wb + (size_t)(n - 1040) * 1024;
        float4 x = src ? *(const float4*)(src + t * 4)
                       : make_float4(0.f, 0.f, 0.f, 0.f);
        x.x *= 64.f; x.y *= 64.f; x.z *= 64.f; x.w *= 64.f;
        f16x4 h, l;
        h[0] = (_Float16)x.x; l[0] = (_Float16)(x.x - (float)h[0]);
        h[1] = (_Float16)x.y; l[1] = (_Float16)(x.y - (float)h[1]);
        h[2] = (_Float16)x.z; l[2] = (_Float16)(x.z - (float)h[2]);
        h[3] = (_Float16)x.w; l[3] = (_Float16)(x.w - (float)h[3]);
        _Float16* base = Bk + (size_t)n * KEXT + t * 4;
        *(f16x4*)(base)        = h;
        *(f16x4*)(base + 1024) = h;
        *(f16x4*)(base + 2048) = l;
        return;
    }
    if (blk < 5184) {             // Wq|Wv -> Bqv (hi only)
        const int n = blk - 3136;
        const float* src = (n < 1024) ? Wq + (size_t)n * 1024
                                      : Wv + (size_t)(n - 1024) * 1024;
        float4 x = *(const float4*)(src + t * 4);
        f16x4 h;
        h[0] = (_Float16)(x.x * 64.f);
        h[1] = (_Float16)(x.y * 64.f);
        h[2] = (_Float16)(x.z * 64.f);
        h[3] = (_Float16)(x.w * 64.f);
        *(f16x4*)(Bqv + (size_t)n * 1024 + t * 4) = h;
        return;
    }
    {                             // Wo -> Be2 (hi only)
        const int n = blk - 5184;
        float4 x = *(const float4*)(Wo + (size_t)n * 1024 + t * 4);
        f16x4 h;
        h[0] = (_Float16)(x.x * 64.f);
        h[1] = (_Float16)(x.y * 64.f);
        h[2] = (_Float16)(x.z * 64.f);
        h[3] = (_Float16)(x.w * 64.f);
        *(f16x4*)(Be2 + (size_t)n * 1024 + t * 4) = h;
    }
}

// ---------------------------------------------------------------------------
// MERGED projection GEMM: 528 blocks.
//   blk <  272: k+ab part — Ae3 @ Bk^T, K=3072, 128x64 tile (17 N-tiles).
//   blk >= 272: q|v part  — Ae3-hi @ Bqv^T, K=1024, 128x128 tile (A row
//               stride KEXT, hi section).
// ---------------------------------------------------------------------------
__global__ __launch_bounds__(256) void mfma_gemm_proj(
    const _Float16* __restrict__ Ae3, const _Float16* __restrict__ Bk,
    const _Float16* __restrict__ Bqv,
    float* __restrict__ qkv, float* __restrict__ ab,
    const float* __restrict__ bq, const float* __restrict__ bk,
    const float* __restrict__ bv)
{
    __shared__ __align__(16) _Float16 As[2][128 * 32];
    __shared__ __align__(16) _Float16 Bs[2][128 * 32];

    const int blk = blockIdx.x;
    const int tid = threadIdx.x;
    const int wave = tid >> 6;
    const int lane = tid & 63;
    const int srow = lane >> 2;
    const int scol = (lane & 3) * 8;
    const int fm = lane & 15;
    const int fq = (lane >> 4) * 8;
    const int rquad = (lane >> 4) * 4;

    if (blk < 272) {
        const int bm = (blk / 17) * 128;
        const int bn = (blk % 17) * 64;
        const int wr = (wave >> 1) * 64;
        const int wc = (wave & 1) * 32;

        const _Float16* gA0 = Ae3 + (size_t)(bm + wave * 32 + srow) * KEXT + scol;
        const _Float16* gA1 = gA0 + (size_t)16 * KEXT;
        const _Float16* gB0 = Bk + (size_t)(bn + wave * 16 + srow) * KEXT + scol;
        _Float16* lA0_0 = &As[0][(wave * 32) * 32];
        _Float16* lA1_0 = &As[0][(wave * 32 + 16) * 32];
        _Float16* lB0_0 = &Bs[0][(wave * 16) * 32];
        _Float16* lA0_1 = &As[1][(wave * 32) * 32];
        _Float16* lA1_1 = &As[1][(wave * 32 + 16) * 32];
        _Float16* lB0_1 = &Bs[1][(wave * 16) * 32];

        f32x4 acc[4][2] = {};

        for (int k0 = 0; k0 < KEXT; k0 += 64) {
            load_lds16(gA0 + k0,      lA0_0);
            load_lds16(gA1 + k0,      lA1_0);
            load_lds16(gB0 + k0,      lB0_0);
            load_lds16(gA0 + k0 + 32, lA0_1);
            load_lds16(gA1 + k0 + 32, lA1_1);
            load_lds16(gB0 + k0 + 32, lB0_1);
            __syncthreads();

            #pragma unroll
            for (int s = 0; s < 2; ++s) {
                f16x8 a[4], b[2];
                #pragma unroll
                for (int mt = 0; mt < 4; ++mt)
                    a[mt] = *(const f16x8*)&As[s][(wr + mt * 16 + fm) * 32 + fq];
                #pragma unroll
                for (int nt = 0; nt < 2; ++nt)
                    b[nt] = *(const f16x8*)&Bs[s][(wc + nt * 16 + fm) * 32 + fq];
                #pragma unroll
                for (int mt = 0; mt < 4; ++mt)
                    #pragma unroll
                    for (int nt = 0; nt < 2; ++nt)
                        acc[mt][nt] = __builtin_amdgcn_mfma_f32_16x16x32_f16(
                            a[mt], b[nt], acc[mt][nt], 0, 0, 0);
            }
            __syncthreads();
        }

        #pragma unroll
        for (int mt = 0; mt < 4; ++mt) {
            #pragma unroll
            for (int nt = 0; nt < 2; ++nt) {
                const int col = bn + wc + nt * 16 + fm;
                #pragma unroll
                for (int i = 0; i < 4; ++i) {
                    const int row = bm + wr + mt * 16 + rquad + i;
                    float val = acc[mt][nt][i] * (1.0f / 1024.0f);
                    if (col < 1024)
                        qkv[(size_t)row * 3072 + 1024 + col] = val + bk[col];
                    else if (col < 1040)
                        ab[(size_t)row * 32 + (col - 1024)] =
                            1.f / (1.f + expf(-val));
                    else if (col < 1056)
                        ab[(size_t)row * 32 + 16 + (col - 1040)] =
                            fmaxf(val, 0.f) + log1pf(expf(-fabsf(val)));
                }
            }
        }
    } else {
        const int n = blk - 272;
        const int bm = (n / 16) * 128;
        const int bn = (n % 16) * 128;
        const int wr = (wave >> 1) * 64;
        const int wc = (wave & 1) * 64;

        // A = hi section of Ae3, row stride KEXT
        const _Float16* gA0 = Ae3 + (size_t)(bm + wave * 32 + srow) * KEXT + scol;
        const _Float16* gA1 = gA0 + (size_t)16 * KEXT;
        const _Float16* gB0 = Bqv + (size_t)(bn + wave * 32 + srow) * 1024 + scol;
        const _Float16* gB1 = gB0 + (size_t)16 * 1024;
        _Float16* lA0_0 = &As[0][(wave * 32) * 32];
        _Float16* lA1_0 = &As[0][(wave * 32 + 16) * 32];
        _Float16* lB0_0 = &Bs[0][(wave * 32) * 32];
        _Float16* lB1_0 = &Bs[0][(wave * 32 + 16) * 32];
        _Float16* lA0_1 = &As[1][(wave * 32) * 32];
        _Float16* lA1_1 = &As[1][(wave * 32 + 16) * 32];
        _Float16* lB0_1 = &Bs[1][(wave * 32) * 32];
        _Float16* lB1_1 = &Bs[1][(wave * 32 + 16) * 32];

        f32x4 acc[4][4] = {};

        for (int k0 = 0; k0 < 1024; k0 += 64) {
            load_lds16(gA0 + k0,      lA0_0);
            load_lds16(gA1 + k0,      lA1_0);
            load_lds16(gB0 + k0,      lB0_0);
            load_lds16(gB1 + k0,      lB1_0);
            load_lds16(gA0 + k0 + 32, lA0_1);
            load_lds16(gA1 + k0 + 32, lA1_1);
            load_lds16(gB0 + k0 + 32, lB0_1);
            load_lds16(gB1 + k0 + 32, lB1_1);
            __syncthreads();

            #pragma unroll
            for (int s = 0; s < 2; ++s) {
                f16x8 a[4], b[4];
                #pragma unroll
                for (int mt = 0; mt < 4; ++mt)
                    a[mt] = *(const f16x8*)&As[s][(wr + mt * 16 + fm) * 32 + fq];
                #pragma unroll
                for (int nt = 0; nt < 4; ++nt)
                    b[nt] = *(const f16x8*)&Bs[s][(wc + nt * 16 + fm) * 32 + fq];
                #pragma unroll
                for (int mt = 0; mt < 4; ++mt)
                    #pragma unroll
                    for (int nt = 0; nt < 4; ++nt)
                        acc[mt][nt] = __builtin_amdgcn_mfma_f32_16x16x32_f16(
                            a[mt], b[nt], acc[mt][nt], 0, 0, 0);
            }
            __syncthreads();
        }

        #pragma unroll
        for (int mt = 0; mt < 4; ++mt) {
            #pragma unroll
            for (int nt = 0; nt < 4; ++nt) {
                const int col = bn + wc + nt * 16 + fm;
                #pragma unroll
                for (int i = 0; i < 4; ++i) {
                    const int row = bm + wr + mt * 16 + rquad + i;
                    float val = acc[mt][nt][i] * (1.0f / 1024.0f);
                    if (col < 1024)
                        qkv[(size_t)row * 3072 + col] = val + bq[col];
                    else
                        qkv[(size_t)row * 3072 + 1024 + col] = val + bv[col - 1024];
                }
            }
        }
    }
}

// ---------------------------------------------------------------------------
// Out-projection MFMA GEMM (unchanged): plain f16, K=1024, 128x64, BK=64.
// ---------------------------------------------------------------------------
__global__ __launch_bounds__(256) void mfma_gemm_out(
    const _Float16* __restrict__ Ae2, const _Float16* __restrict__ Be2,
    float* __restrict__ outp, const float* __restrict__ bo)
{
    __shared__ __align__(16) _Float16 As[2][128 * 32];
    __shared__ __align__(16) _Float16 Bs[2][64 * 32];

    const int tid = threadIdx.x;
    const int wave = tid >> 6;
    const int lane = tid & 63;
    const int bm = blockIdx.y * 128;
    const int bn = blockIdx.x * 64;
    const int wr = (wave >> 1) * 64;
    const int wc = (wave & 1) * 32;

    const int srow = lane >> 2;
    const int scol = (lane & 3) * 8;
    const _Float16* gA0 = Ae2 + (size_t)(bm + wave * 32 + srow) * 1024 + scol;
    const _Float16* gA1 = gA0 + (size_t)16 * 1024;
    const _Float16* gB0 = Be2 + (size_t)(bn + wave * 16 + srow) * 1024 + scol;
    _Float16* lA0_0 = &As[0][(wave * 32) * 32];
    _Float16* lA1_0 = &As[0][(wave * 32 + 16) * 32];
    _Float16* lB0_0 = &Bs[0][(wave * 16) * 32];
    _Float16* lA0_1 = &As[1][(wave * 32) * 32];
    _Float16* lA1_1 = &As[1][(wave * 32 + 16) * 32];
    _Float16* lB0_1 = &Bs[1][(wave * 16) * 32];

    const int fm = lane & 15;
    const int fq = (lane >> 4) * 8;

    f32x4 acc[4][2] = {};

    for (int k0 = 0; k0 < 1024; k0 += 64) {
        load_lds16(gA0 + k0,      lA0_0);
        load_lds16(gA1 + k0,      lA1_0);
        load_lds16(gB0 + k0,      lB0_0);
        load_lds16(gA0 + k0 + 32, lA0_1);
        load_lds16(gA1 + k0 + 32, lA1_1);
        load_lds16(gB0 + k0 + 32, lB0_1);
        __syncthreads();

        #pragma unroll
        for (int s = 0; s < 2; ++s) {
            f16x8 a[4], b[2];
            #pragma unroll
            for (int mt = 0; mt < 4; ++mt)
                a[mt] = *(const f16x8*)&As[s][(wr + mt * 16 + fm) * 32 + fq];
            #pragma unroll
            for (int nt = 0; nt < 2; ++nt)
                b[nt] = *(const f16x8*)&Bs[s][(wc + nt * 16 + fm) * 32 + fq];
            #pragma unroll
            for (int mt = 0; mt < 4; ++mt)
                #pragma unroll
                for (int nt = 0; nt < 2; ++nt)
                    acc[mt][nt] = __builtin_amdgcn_mfma_f32_16x16x32_f16(
                        a[mt], b[nt], acc[mt][nt], 0, 0, 0);
        }
        __syncthreads();
    }

    const int rquad = (lane >> 4) * 4;
    #pragma unroll
    for (int mt = 0; mt < 4; ++mt) {
        #pragma unroll
        for (int nt = 0; nt < 2; ++nt) {
            const int col = bn + wc + nt * 16 + fm;
            #pragma unroll
            for (int i = 0; i < 4; ++i) {
                const int row = bm + wr + mt * 16 + rquad + i;
                outp[(size_t)row * 1024 + col] = acc[mt][nt][i] * 64.f + bo[col];
            }
        }
    }
}

// ---------------------------------------------------------------------------
// DPP 16-lane reduction (xor1, xor2, row_ror:4, row_ror:8 -> all lanes hold sum)
// ---------------------------------------------------------------------------
template <int CTRL>
__device__ __forceinline__ float dpp_addf(float x) {
    int y = __builtin_amdgcn_update_dpp(0, __builtin_bit_cast(int, x),
                                        CTRL, 0xF, 0xF, true);
    return x + __builtin_bit_cast(float, y);
}
__device__ __forceinline__ float red16(float x) {
    x = dpp_addf<0xB1>(x);
    x = dpp_addf<0x4E>(x);
    x = dpp_addf<0x124>(x);
    x = dpp_addf<0x128>(x);
    return x;
}

// ---------------------------------------------------------------------------
// Gated delta recurrence — r11 VERBATIM (120.7 us, best measured; both
// lookahead variants r6/r12 regressed: the loop is issue-bound, do not add
// instructions). 512 blocks x 64 threads; blk%32 = chain (XCD co-location),
// blk/32 = 4-row slice; distance-2 LDS->reg prefetch.
// ---------------------------------------------------------------------------
__global__ __launch_bounds__(64) void gdn_recurrence(
    const float* __restrict__ qkv, const float* __restrict__ ab,
    float* __restrict__ att)
{
    __shared__ __align__(16) float ks[2][RCT][64];
    __shared__ __align__(16) float qs[2][RCT][64];
    __shared__ __align__(16) float vs_[2][RCT][4];
    __shared__ __align__(16) float gab[2][RCT][2];

    const int blk = blockIdx.x;
    const int bh = blk & 31;          // chain (XCD co-location)
    const int s  = blk >> 5;          // row-slice 0..15
    const int b  = bh >> 4;
    const int h  = bh & 15;
    const int lane = threadIdx.x;
    const int rl = lane >> 4;         // local row 0..3
    const int el = lane & 15;         // e-slice
    const int e0 = el * 4;
    const int r0 = s * 4;

    const float* qb  = qkv + (size_t)b * LL * 3072 + h * 64;
    const float* kb  = qb + 1024;
    const float* vb  = qb + 2048 + r0;
    const float* abp = ab + (size_t)b * LL * 32 + h;
    float* op = att + ((size_t)(b * NH + h) * DD + r0 + rl) * LL;

    const int st = lane >> 4;          // t-within-4 for staging
    const int sd = (lane & 15) * 4;    // d offset

    float S0 = 0.f, S1 = 0.f, S2 = 0.f, S3 = 0.f;

    // ---- async-stage k/q chunk 0, reg-load v/ab chunk 0 ----
    {
        const size_t ro = (size_t)st * 3072 + sd;
        #pragma unroll
        for (int m = 0; m < 8; ++m) {
            load_lds16(kb + ro + (size_t)m * 4 * 3072, &ks[0][m * 4][0]);
            load_lds16(qb + ro + (size_t)m * 4 * 3072, &qs[0][m * 4][0]);
        }
        float4 pv = make_float4(0.f,0.f,0.f,0.f);
        if (lane < RCT) pv = *(const float4*)(vb + (size_t)lane * 3072);
        float pab = (lane < 32) ? abp[(size_t)lane * 32]
                                : abp[(size_t)(lane - 32) * 32 + 16];
        if (lane < RCT) *(float4*)&vs_[0][lane][0] = pv;
        if (lane < 32) gab[0][lane][0] = pab;
        else           gab[0][lane - 32][1] = pab;
    }
    __syncthreads();

    const int NCHUNK = LL / RCT;
    for (int c = 0; c < NCHUNK; ++c) {
        const int cur = c & 1, nxt = cur ^ 1;
        const bool more = (c + 1 < NCHUNK);

        // issue async staging for chunk c+1; tiny reg prefetch for v/ab
        float4 pv = make_float4(0.f,0.f,0.f,0.f);
        float pab = 0.f;
        if (more) {
            const size_t t0 = (size_t)(c + 1) * RCT;
            const size_t ro = (t0 + st) * 3072 + sd;
            #pragma unroll
            for (int m = 0; m < 8; ++m) {
                load_lds16(kb + ro + (size_t)m * 4 * 3072, &ks[nxt][m * 4][0]);
                load_lds16(qb + ro + (size_t)m * 4 * 3072, &qs[nxt][m * 4][0]);
            }
            if (lane < RCT) pv = *(const float4*)(vb + (t0 + lane) * 3072);
            pab = (lane < 32) ? abp[(t0 + lane) * 32]
                              : abp[(t0 + lane - 32) * 32 + 16];
        }

        // ---- 32 steps, distance-2 LDS->reg prefetch (4-slot circular) ----
        float4 kr[4], qr[4];
        float vr[4];
        float2 abr[4];
        #pragma unroll
        for (int i = 0; i < 2; ++i) {
            kr[i] = *(const float4*)&ks[cur][i][e0];
            qr[i] = *(const float4*)&qs[cur][i][e0];
            vr[i] = vs_[cur][i][rl];
            abr[i] = *(const float2*)&gab[cur][i][0];
        }

        float o0 = 0.f, o1 = 0.f, o2 = 0.f;
        #pragma unroll 4
        for (int t = 0; t < RCT; ++t) {
            const int tf = (t + 2 < RCT) ? t + 2 : RCT - 1;
            kr[(t + 2) & 3] = *(const float4*)&ks[cur][tf][e0];
            qr[(t + 2) & 3] = *(const float4*)&qs[cur][tf][e0];
            vr[(t + 2) & 3] = vs_[cur][tf][rl];
            abr[(t + 2) & 3] = *(const float2*)&gab[cur][tf][0];

            const float4 kc = kr[t & 3];
            const float4 qc = qr[t & 3];
            const float vc = vr[t & 3];
            const float ac = abr[t & 3].x;
            const float bc = abr[t & 3].y;

            // sk = (S . k) row-dot
            float p0 = fmaf(S1, kc.y, S0 * kc.x);
            float p1 = fmaf(S3, kc.w, S2 * kc.z);
            float sk = red16(p0 + p1);

            const float cf = bc * fmaf(-ac, sk, vc);

            S0 = fmaf(ac, S0, cf * kc.x);
            S1 = fmaf(ac, S1, cf * kc.y);
            S2 = fmaf(ac, S2, cf * kc.z);
            S3 = fmaf(ac, S3, cf * kc.w);

            float q0 = fmaf(S1, qc.y, S0 * qc.x);
            float q1 = fmaf(S3, qc.w, S2 * qc.z);
            float o = red16(q0 + q1);

            const int ph = t & 3;
            if (ph == 0) o0 = o;
            else if (ph == 1) o1 = o;
            else if (ph == 2) o2 = o;
            else if (el == 0)
                *(float4*)(op + c * RCT + t - 3) = make_float4(o0, o1, o2, o);
        }

        // commit v/ab prefetch into next buffer, then publish
        if (more) {
            if (lane < RCT) *(float4*)&vs_[nxt][lane][0] = pv;
            if (lane < 32) gab[nxt][lane][0] = pab;
            else           gab[nxt][lane - 32][1] = pab;
        }
        __syncthreads();
    }
}

// ---------------------------------------------------------------------------
// Fused: residual depthwise causal conv (bug-compat reshaped view) +
// transpose back + f16 convert (hi only) for the out-projection A matrix.
// ---------------------------------------------------------------------------
__global__ __launch_bounds__(256) void conv_convert(
    const float* __restrict__ att, const float* __restrict__ Wconv,
    _Float16* __restrict__ Ae2)
{
    __shared__ float yt[112][68];
    const int lb = blockIdx.x;
    const int h  = blockIdx.y;
    const int b  = blockIdx.z;
    const int tid = threadIdx.x;

    {
        const int d = tid >> 2;
        const int part = tid & 3;
        const float* src  = att + ((size_t)(b * NH + h) * DD + d) * LL;
        const float* srcm = src - (size_t)DD * LL;
        #pragma unroll
        for (int m = 0; m < 7; ++m) {
            const int off = (part * 7 + m) * 4;
            const int lg = lb * 64 - 48 + off;
            float4 v;
            if (lg >= 0)      v = *(const float4*)(src + lg);
            else if (h > 0)   v = *(const float4*)(srcm + lg + 1024);
            else              v = make_float4(0.f, 0.f, 0.f, 0.f);
            yt[off + 0][d] = v.x; yt[off + 1][d] = v.y;
            yt[off + 2][d] = v.z; yt[off + 3][d] = v.w;
        }
    }
    __syncthreads();

    float4 w[4];
    #pragma unroll
    for (int k = 0; k < 4; ++k)
        w[k] = ((const float4*)Wconv)[tid * 4 + k];

    const int d0 = (tid & 15) * 4;
    const int lq = tid >> 4;
    const float sc = 1.f / 4096.f;

    #pragma unroll
    for (int rr = 0; rr < 4; ++rr) {
        const int ll = rr * 16 + lq;
        float y0[4], y1[4], y2[4], y3[4];
        *(float4*)y0 = *(const float4*)&yt[ll +  0][d0];
        *(float4*)y1 = *(const float4*)&yt[ll + 16][d0];
        *(float4*)y2 = *(const float4*)&yt[ll + 32][d0];
        *(float4*)y3 = *(const float4*)&yt[ll + 48][d0];
        f16x4 hi;
        #pragma unroll
        for (int k = 0; k < 4; ++k) {
            float acc = y3[k];
            acc = fmaf(w[k].x, y0[k], acc);
            acc = fmaf(w[k].y, y1[k], acc);
            acc = fmaf(w[k].z, y2[k], acc);
            acc = fmaf(w[k].w, y3[k], acc);
            hi[k] = (_Float16)(acc * sc);
        }
        const size_t row = (size_t)b * 1024 + h * 64 + lb * 4 + rr;
        *(f16x4*)(Ae2 + row * 1024 + tid * 4) = hi;
    }
}

// ---------------------------------------------------------------------------
extern "C" void kernel_launch(void* const* d_in, const int* in_sizes, int n_in,
                              void* d_out, int out_size, void* d_ws, size_t ws_size,
                              hipStream_t stream)
{
    const float* hs    = (const float*)d_in[0];
    const float* Wq    = (const float*)d_in[1];
    const float* bq    = (const float*)d_in[2];
    const float* Wk    = (const float*)d_in[3];
    const float* bk    = (const float*)d_in[4];
    const float* Wv    = (const float*)d_in[5];
    const float* bv    = (const float*)d_in[6];
    const float* Wa    = (const float*)d_in[7];
    const float* Wb    = (const float*)d_in[8];
    const float* Wconv = (const float*)d_in[9];
    const float* Wo    = (const float*)d_in[10];
    const float* bo    = (const float*)d_in[11];
    float* out = (float*)d_out;

    // workspace layout (~63 MB)
    char* w = (char*)d_ws;
    float* qkv = (float*)w;        w += (size_t)MM * 3072 * 4;      // 25.2 MB
    float* att = (float*)w;        w += (size_t)MM * 1024 * 4;      //  8.4 MB ([B][NH][D][L])
    float* ab  = (float*)w;        w += (size_t)MM * 32 * 4;        //  0.26 MB
    _Float16* Ae3 = (_Float16*)w;  w += (size_t)MM * KEXT * 2;      // 12.6 MB
    _Float16* Bk  = (_Float16*)w;  w += (size_t)NBK * KEXT * 2;     //  6.7 MB
    _Float16* Bqv = (_Float16*)w;  w += (size_t)2048 * 1024 * 2;    //  4.2 MB
    _Float16* Ae2 = (_Float16*)w;  w += (size_t)MM * 1024 * 2;      //  4.2 MB
    _Float16* Be2 = (_Float16*)w;  w += (size_t)1024 * 1024 * 2;    //  2.1 MB

    // 1) conversions (hs->Ae3, Wk/Wa/Wb->Bk, Wq|Wv->Bqv, Wo->Be2)
    hipLaunchKernelGGL(convert_front, dim3(6208), dim3(256), 0, stream,
                       hs, Wq, Wk, Wv, Wa, Wb, Wo, Ae3, Bk, Bqv, Be2);

    // 2) merged projection GEMM (k+ab 272 blocks | q+v 256 blocks)
    hipLaunchKernelGGL(mfma_gemm_proj, dim3(528), dim3(256), 0, stream,
                       Ae3, Bk, Bqv, qkv, ab, bq, bk, bv);

    // 3) gated delta recurrence (r11 verbatim, 512 one-wave blocks)
    hipLaunchKernelGGL(gdn_recurrence, dim3(512), dim3(64), 0, stream, qkv, ab, att);

    // 4) fused conv + transpose + f16 convert (hi only, writes Ae2)
    hipLaunchKernelGGL(conv_convert, dim3(16, 16, BB), dim3(256), 0, stream,
                       att, Wconv, Ae2);

    // 5) out-projection (plain f16, K=1024, 128x64 tiles -> 256 blocks)
    hipLaunchKernelGGL(mfma_gemm_out, dim3(1024 / 64, MM / 128), dim3(256), 0, stream,
                       Ae2, Be2, out, bo);
}